// Round 1
// baseline (829.287 us; speedup 1.0000x reference)
//
#include <hip/hip_runtime.h>

static constexpr int NND = 100000;   // nodes
static constexpr int NED = 3200000;  // edges (before self-loops)

// ---------------- kernels ----------------

__global__ void k_deg(const int* __restrict__ dst, int* __restrict__ deg, int e) {
    int stride = gridDim.x * blockDim.x;
    for (int i = blockIdx.x * blockDim.x + threadIdx.x; i < e; i += stride)
        atomicAdd(&deg[dst[i]], 1);
}

__global__ void k_dinv(const int* __restrict__ deg, float* __restrict__ dinv, int n) {
    int i = blockIdx.x * blockDim.x + threadIdx.x;
    if (i < n) dinv[i] = rsqrtf((float)(deg[i] + 1));  // +1 = self-loop
}

// t[n,:] = (x[n,:] @ W) * dinv[n]
template<int FIN, int FOUT>
__global__ void k_xw(const float* __restrict__ x, const float* __restrict__ W,
                     const float* __restrict__ dinv, float* __restrict__ t, int n) {
    __shared__ float sW[FIN * FOUT];
    for (int i = threadIdx.x; i < FIN * FOUT; i += blockDim.x) sW[i] = W[i];
    __syncthreads();
    int nd = blockIdx.x * blockDim.x + threadIdx.x;
    if (nd >= n) return;
    float xi[FIN];
#pragma unroll
    for (int k = 0; k < FIN; ++k) xi[k] = x[(size_t)nd * FIN + k];
    float d = dinv[nd];
#pragma unroll
    for (int j = 0; j < FOUT; ++j) {
        float acc = 0.f;
#pragma unroll
        for (int k = 0; k < FIN; ++k) acc = fmaf(xi[k], sW[k * FOUT + j], acc);
        t[(size_t)nd * FOUT + j] = acc * d;
    }
}

// u[dst[e],f] += t[src[e],f]  — one thread per (edge, feature)
template<int LOGF>
__global__ void k_scatter(const int* __restrict__ src, const int* __restrict__ dst,
                          const float* __restrict__ t, float* __restrict__ u, int e) {
    constexpr int F = 1 << LOGF;
    long long total = (long long)e << LOGF;
    long long stride = (long long)gridDim.x * blockDim.x;
    for (long long i = (long long)blockIdx.x * blockDim.x + threadIdx.x; i < total; i += stride) {
        int ed = (int)(i >> LOGF);
        int f  = (int)i & (F - 1);
        int s = src[ed];
        int d = dst[ed];
        atomicAdd(&u[((size_t)d << LOGF) + f], t[((size_t)s << LOGF) + f]);
    }
}

// out[n,f] = act( dinv[n]*(u[n,f] + t[n,f]) + b[f] )
template<int F, bool RELU>
__global__ void k_final(const float* __restrict__ u, const float* __restrict__ t,
                        const float* __restrict__ dinv, const float* __restrict__ b,
                        float* __restrict__ out, int n) {
    int i = blockIdx.x * blockDim.x + threadIdx.x;
    if (i >= n * F) return;
    int nd = i / F, f = i % F;
    float v = fmaf(dinv[nd], u[i] + t[i], b[f]);
    out[i] = RELU ? fmaxf(v, 0.f) : v;
}

// ---------------- launch ----------------

static inline size_t align256(size_t x) { return (x + 255) & ~(size_t)255; }

extern "C" void kernel_launch(void* const* d_in, const int* in_sizes, int n_in,
                              void* d_out, int out_size, void* d_ws, size_t ws_size,
                              hipStream_t stream) {
    const float* x  = (const float*)d_in[0];
    const int*   ei = (const int*)d_in[1];
    const float* W1 = (const float*)d_in[2];
    const float* b1 = (const float*)d_in[3];
    const float* W2 = (const float*)d_in[4];
    const float* b2 = (const float*)d_in[5];
    const float* W3 = (const float*)d_in[6];
    const float* b3 = (const float*)d_in[7];
    float* out = (float*)d_out;

    const int* src = ei;
    const int* dst = ei + NED;

    char* p = (char*)d_ws;
    float* dinv = (float*)p; p += align256(sizeof(float) * (size_t)NND);
    int*   deg  = (int*)p;   p += align256(sizeof(int) * (size_t)NND);
    float* t    = (float*)p; p += align256(sizeof(float) * (size_t)NND * 32);
    float* u    = (float*)p; p += align256(sizeof(float) * (size_t)NND * 32);
    float* h    = (float*)p; p += align256(sizeof(float) * (size_t)NND * 32);

    const int B = 256;
    const int gridN   = (NND + B - 1) / B;

    // degree + dinv (shared across layers)
    hipMemsetAsync(deg, 0, sizeof(int) * (size_t)NND, stream);
    k_deg<<<2048, B, 0, stream>>>(dst, deg, NED);
    k_dinv<<<gridN, B, 0, stream>>>(deg, dinv, NND);

    // ---- layer 1: 3 -> 16, relu ----
    k_xw<3, 16><<<gridN, B, 0, stream>>>(x, W1, dinv, t, NND);
    hipMemsetAsync(u, 0, sizeof(float) * (size_t)NND * 16, stream);
    k_scatter<4><<<4096, B, 0, stream>>>(src, dst, t, u, NED);
    k_final<16, true><<<(NND * 16 + B - 1) / B, B, 0, stream>>>(u, t, dinv, b1, h, NND);

    // ---- layer 2: 16 -> 32, relu ----
    k_xw<16, 32><<<gridN, B, 0, stream>>>(h, W2, dinv, t, NND);
    hipMemsetAsync(u, 0, sizeof(float) * (size_t)NND * 32, stream);
    k_scatter<5><<<4096, B, 0, stream>>>(src, dst, t, u, NED);
    k_final<32, true><<<(NND * 32 + B - 1) / B, B, 0, stream>>>(u, t, dinv, b2, h, NND);

    // ---- layer 3: 32 -> 2, no relu ----
    k_xw<32, 2><<<gridN, B, 0, stream>>>(h, W3, dinv, t, NND);
    hipMemsetAsync(u, 0, sizeof(float) * (size_t)NND * 2, stream);
    k_scatter<1><<<4096, B, 0, stream>>>(src, dst, t, u, NED);
    k_final<2, false><<<(NND * 2 + B - 1) / B, B, 0, stream>>>(u, t, dinv, b3, out, NND);
}

// Round 2
// 529.853 us; speedup vs baseline: 1.5651x; 1.5651x over previous
//
#include <hip/hip_runtime.h>

static constexpr int NND = 100000;   // nodes
static constexpr int NED = 3200000;  // edges (before self-loops)

// ---------------- degree / dinv ----------------

__global__ void k_deg(const int* __restrict__ dst, int* __restrict__ deg, int e) {
    int i = blockIdx.x * blockDim.x + threadIdx.x;
    if (i < e) atomicAdd(&deg[dst[i]], 1);
}

__global__ void k_dinv(const int* __restrict__ deg, float* __restrict__ dinv, int n) {
    int i = blockIdx.x * blockDim.x + threadIdx.x;
    if (i < n) dinv[i] = rsqrtf((float)(deg[i] + 1));  // +1 = self-loop
}

// ---------------- scan (exclusive) for CSR rowptr ----------------
// chunk = 1024 elems per block (256 thr x 4)

__global__ void k_scan1(const int* __restrict__ deg, int* __restrict__ excl,
                        int* __restrict__ blockSums, int n) {
    __shared__ int lds[256];
    int tid = threadIdx.x;
    int base = blockIdx.x * 1024 + tid * 4;
    int v[4]; int sum = 0;
#pragma unroll
    for (int k = 0; k < 4; ++k) { int idx = base + k; v[k] = (idx < n) ? deg[idx] : 0; sum += v[k]; }
    lds[tid] = sum; __syncthreads();
    for (int off = 1; off < 256; off <<= 1) {
        int x = lds[tid];
        int y = (tid >= off) ? lds[tid - off] : 0;
        __syncthreads();
        lds[tid] = x + y;
        __syncthreads();
    }
    int run = lds[tid] - sum;  // exclusive offset of this thread within block
#pragma unroll
    for (int k = 0; k < 4; ++k) { int idx = base + k; if (idx < n) excl[idx] = run; run += v[k]; }
    if (tid == 0) blockSums[blockIdx.x] = lds[255];
}

__global__ void k_scan2(int* __restrict__ blockSums, int nb) {  // single block, 128 thr
    __shared__ int lds[128];
    int tid = threadIdx.x;
    int v = (tid < nb) ? blockSums[tid] : 0;
    lds[tid] = v; __syncthreads();
    for (int off = 1; off < 128; off <<= 1) {
        int x = lds[tid];
        int y = (tid >= off) ? lds[tid - off] : 0;
        __syncthreads();
        lds[tid] = x + y;
        __syncthreads();
    }
    if (tid < nb) blockSums[tid] = lds[tid] - v;  // exclusive
}

__global__ void k_scan3(int* __restrict__ excl, const int* __restrict__ blockSums,
                        int n, int e) {
    int i = blockIdx.x * blockDim.x + threadIdx.x;
    if (i < n) excl[i] += blockSums[i >> 10];
    if (i == n) excl[n] = e;
}

// ---------------- CSR fill ----------------

__global__ void k_fill(const int* __restrict__ src, const int* __restrict__ dst,
                       const int* __restrict__ rowptr, int* __restrict__ cursor,
                       int* __restrict__ ssrc, int e) {
    int i = blockIdx.x * blockDim.x + threadIdx.x;
    if (i >= e) return;
    int d = dst[i];
    int pos = rowptr[d] + atomicAdd(&cursor[d], 1);
    ssrc[pos] = src[i];
}

// ---------------- dense t = (x @ W) * dinv ----------------

template<int FIN, int FOUT>
__global__ void k_xw(const float* __restrict__ x, const float* __restrict__ W,
                     const float* __restrict__ dinv, float* __restrict__ t, int n) {
    __shared__ float sW[FIN * FOUT];
    for (int i = threadIdx.x; i < FIN * FOUT; i += blockDim.x) sW[i] = W[i];
    __syncthreads();
    int nd = blockIdx.x * blockDim.x + threadIdx.x;
    if (nd >= n) return;
    float xi[FIN];
#pragma unroll
    for (int k = 0; k < FIN; ++k) xi[k] = x[(size_t)nd * FIN + k];
    float d = dinv[nd];
#pragma unroll
    for (int j = 0; j < FOUT; ++j) {
        float acc = 0.f;
#pragma unroll
        for (int k = 0; k < FIN; ++k) acc = fmaf(xi[k], sW[k * FOUT + j], acc);
        t[(size_t)nd * FOUT + j] = acc * d;
    }
}

// ---------------- gather-aggregate + epilogue ----------------
// out[n, f0:f0+VEC] = act( dinv[n] * (t[n] + sum_{j in CSR(n)} t[ssrc[j]]) + b )

template<int F, int VEC, bool RELU>
__global__ void k_gather(const int* __restrict__ rowptr, const int* __restrict__ ssrc,
                         const float* __restrict__ t, const float* __restrict__ dinv,
                         const float* __restrict__ b, float* __restrict__ out, int n) {
    constexpr int TPN = F / VEC;  // threads per node (power of 2)
    int i = blockIdx.x * blockDim.x + threadIdx.x;
    int node = i / TPN;
    int fv = i % TPN;
    if (node >= n) return;
    int f0 = fv * VEC;

    float acc[VEC];
    // self-loop term
    {
        const float* trow = t + (size_t)node * F + f0;
        if constexpr (VEC == 4) {
            float4 v = *reinterpret_cast<const float4*>(trow);
            acc[0] = v.x; acc[1] = v.y; acc[2] = v.z; acc[3] = v.w;
        } else {
            float2 v = *reinterpret_cast<const float2*>(trow);
            acc[0] = v.x; acc[1] = v.y;
        }
    }
    int beg = rowptr[node], end = rowptr[node + 1];
    for (int j = beg; j < end; ++j) {
        int s = ssrc[j];
        const float* trow = t + (size_t)s * F + f0;
        if constexpr (VEC == 4) {
            float4 v = *reinterpret_cast<const float4*>(trow);
            acc[0] += v.x; acc[1] += v.y; acc[2] += v.z; acc[3] += v.w;
        } else {
            float2 v = *reinterpret_cast<const float2*>(trow);
            acc[0] += v.x; acc[1] += v.y;
        }
    }
    float d = dinv[node];
    float* orow = out + (size_t)node * F + f0;
#pragma unroll
    for (int k = 0; k < VEC; ++k) {
        float v = fmaf(d, acc[k], b[f0 + k]);
        orow[k] = RELU ? fmaxf(v, 0.f) : v;
    }
}

// ---------------- launch ----------------

static inline size_t align256(size_t x) { return (x + 255) & ~(size_t)255; }

extern "C" void kernel_launch(void* const* d_in, const int* in_sizes, int n_in,
                              void* d_out, int out_size, void* d_ws, size_t ws_size,
                              hipStream_t stream) {
    const float* x  = (const float*)d_in[0];
    const int*   ei = (const int*)d_in[1];
    const float* W1 = (const float*)d_in[2];
    const float* b1 = (const float*)d_in[3];
    const float* W2 = (const float*)d_in[4];
    const float* b2 = (const float*)d_in[5];
    const float* W3 = (const float*)d_in[6];
    const float* b3 = (const float*)d_in[7];
    float* out = (float*)d_out;

    const int* src = ei;
    const int* dst = ei + NED;

    char* p = (char*)d_ws;
    float* dinv    = (float*)p; p += align256(sizeof(float) * (size_t)NND);
    int*   deg     = (int*)p;   p += align256(sizeof(int) * (size_t)NND);
    int*   rowptr  = (int*)p;   p += align256(sizeof(int) * (size_t)(NND + 1));
    int*   cursor  = (int*)p;   p += align256(sizeof(int) * (size_t)NND);
    int*   bsums   = (int*)p;   p += align256(sizeof(int) * 128);
    int*   ssrc    = (int*)p;   p += align256(sizeof(int) * (size_t)NED);
    float* buf0    = (float*)p; p += align256(sizeof(float) * (size_t)NND * 32);
    float* buf1    = (float*)p; p += align256(sizeof(float) * (size_t)NND * 32);

    const int B = 256;
    const int gridN = (NND + B - 1) / B;
    const int gridE = (NED + B - 1) / B;
    const int nScanBlocks = (NND + 1023) / 1024;  // 98

    // ---- preprocessing: degree, dinv, CSR ----
    hipMemsetAsync(deg, 0, sizeof(int) * (size_t)NND, stream);
    hipMemsetAsync(cursor, 0, sizeof(int) * (size_t)NND, stream);
    k_deg<<<gridE, B, 0, stream>>>(dst, deg, NED);
    k_dinv<<<gridN, B, 0, stream>>>(deg, dinv, NND);
    k_scan1<<<nScanBlocks, 256, 0, stream>>>(deg, rowptr, bsums, NND);
    k_scan2<<<1, 128, 0, stream>>>(bsums, nScanBlocks);
    k_scan3<<<(NND + 1 + B - 1) / B, B, 0, stream>>>(rowptr, bsums, NND, NED);
    k_fill<<<gridE, B, 0, stream>>>(src, dst, rowptr, cursor, ssrc, NED);

    // ---- layer 1: 3 -> 16, relu ----
    k_xw<3, 16><<<gridN, B, 0, stream>>>(x, W1, dinv, buf0, NND);
    k_gather<16, 4, true><<<(NND * 4 + B - 1) / B, B, 0, stream>>>(rowptr, ssrc, buf0, dinv, b1, buf1, NND);

    // ---- layer 2: 16 -> 32, relu ----
    k_xw<16, 32><<<gridN, B, 0, stream>>>(buf1, W2, dinv, buf0, NND);
    k_gather<32, 4, true><<<(NND * 8 + B - 1) / B, B, 0, stream>>>(rowptr, ssrc, buf0, dinv, b2, buf1, NND);

    // ---- layer 3: 32 -> 2, no relu ----
    k_xw<32, 2><<<gridN, B, 0, stream>>>(buf1, W3, dinv, buf0, NND);
    k_gather<2, 2, false><<<(NND + B - 1) / B, B, 0, stream>>>(rowptr, ssrc, buf0, dinv, b3, out, NND);
}

// Round 3
// 249.262 us; speedup vs baseline: 3.3270x; 2.1257x over previous
//
#include <hip/hip_runtime.h>

static constexpr int NND = 100000;        // nodes
static constexpr int NED = 3200000;       // edges (before self-loops)
static constexpr int NB  = (NND + 255) / 256;   // 391 buckets of 256 nodes
static constexpr int NCHUNK = 256;              // edge chunks
static constexpr int EPC = NED / NCHUNK;        // 12500 edges per chunk
static constexpr int SCAN_N = NB * NCHUNK;      // 100096

// ---------------- partition pass 1: per-(chunk,bucket) histogram ----------------

__global__ void k_hist(const int* __restrict__ dst, int* __restrict__ counts) {
    __shared__ int h[NB];
    for (int i = threadIdx.x; i < NB; i += 256) h[i] = 0;
    __syncthreads();
    int c = blockIdx.x;
    int base = c * EPC;
    for (int i = threadIdx.x; i < EPC; i += 256)
        atomicAdd(&h[dst[base + i] >> 8], 1);
    __syncthreads();
    for (int b = threadIdx.x; b < NB; b += 256)
        counts[b * NCHUNK + c] = h[b];   // bucket-major for the scan
}

// ---------------- scan (exclusive), 1024 elems/block ----------------

__global__ void k_scan1(const int* __restrict__ in, int* __restrict__ excl,
                        int* __restrict__ blockSums, int n) {
    __shared__ int lds[256];
    int tid = threadIdx.x;
    int base = blockIdx.x * 1024 + tid * 4;
    int v[4]; int sum = 0;
#pragma unroll
    for (int k = 0; k < 4; ++k) { int idx = base + k; v[k] = (idx < n) ? in[idx] : 0; sum += v[k]; }
    lds[tid] = sum; __syncthreads();
    for (int off = 1; off < 256; off <<= 1) {
        int x = lds[tid];
        int y = (tid >= off) ? lds[tid - off] : 0;
        __syncthreads();
        lds[tid] = x + y;
        __syncthreads();
    }
    int run = lds[tid] - sum;
#pragma unroll
    for (int k = 0; k < 4; ++k) { int idx = base + k; if (idx < n) excl[idx] = run; run += v[k]; }
    if (tid == 0) blockSums[blockIdx.x] = lds[255];
}

__global__ void k_scan2(int* __restrict__ blockSums, int nb) {  // single block, 128 thr
    __shared__ int lds[128];
    int tid = threadIdx.x;
    int v = (tid < nb) ? blockSums[tid] : 0;
    lds[tid] = v; __syncthreads();
    for (int off = 1; off < 128; off <<= 1) {
        int x = lds[tid];
        int y = (tid >= off) ? lds[tid - off] : 0;
        __syncthreads();
        lds[tid] = x + y;
        __syncthreads();
    }
    if (tid < nb) blockSums[tid] = lds[tid] - v;
}

__global__ void k_scan3(int* __restrict__ excl, const int* __restrict__ blockSums,
                        int n, int e) {
    int i = blockIdx.x * blockDim.x + threadIdx.x;
    if (i < n) excl[i] += blockSums[i >> 10];
    if (i == n) excl[n] = e;
}

// ---------------- partition pass 2: scatter into bucket runs ----------------
// pack = src | (dst&255)<<20   (src < 2^20)

__global__ void k_part(const int* __restrict__ src, const int* __restrict__ dst,
                       const int* __restrict__ excl, int* __restrict__ tmp) {
    __shared__ int cur[NB];
    int c = blockIdx.x;
    for (int b = threadIdx.x; b < NB; b += 256) cur[b] = excl[b * NCHUNK + c];
    __syncthreads();
    int base = c * EPC;
    for (int i = threadIdx.x; i < EPC; i += 256) {
        int d = dst[base + i];
        int s = src[base + i];
        int b = d >> 8;
        int pos = atomicAdd(&cur[b], 1);
        tmp[pos] = s | ((d & 255) << 20);
    }
}

// ---------------- per-bucket: deg/dinv/rowptr + final CSR fill ----------------

__global__ void k_bucket(const int* __restrict__ excl, const int* __restrict__ tmp,
                         int* __restrict__ ssrc, int* __restrict__ rowptr,
                         float* __restrict__ dinv) {
    __shared__ int cnt[256];
    __shared__ int lds[256];
    int b = blockIdx.x, t = threadIdx.x;
    int start = excl[b * NCHUNK];
    int end   = excl[(b + 1) * NCHUNK];   // excl[SCAN_N] == NED for last bucket
    cnt[t] = 0;
    __syncthreads();
    for (int i = start + t; i < end; i += 256)
        atomicAdd(&cnt[tmp[i] >> 20], 1);
    __syncthreads();
    int v = cnt[t];
    lds[t] = v; __syncthreads();
    for (int off = 1; off < 256; off <<= 1) {
        int x = lds[t];
        int y = (t >= off) ? lds[t - off] : 0;
        __syncthreads();
        lds[t] = x + y;
        __syncthreads();
    }
    int node = b * 256 + t;
    int rp = start + lds[t] - v;          // global CSR row start
    if (node < NND) {
        rowptr[node] = rp;
        dinv[node] = rsqrtf((float)(v + 1));  // +1 self-loop
    }
    if (b == 0 && t == 0) rowptr[NND] = NED;
    cnt[t] = rp;                          // reuse as running cursor
    __syncthreads();
    for (int i = start + t; i < end; i += 256) {
        int p = tmp[i];
        int pos = atomicAdd(&cnt[p >> 20], 1);
        ssrc[pos] = p & 0xFFFFF;
    }
}

// ---------------- dense t = (x @ W) * dinv ----------------

template<int FIN, int FOUT>
__global__ void k_xw(const float* __restrict__ x, const float* __restrict__ W,
                     const float* __restrict__ dinv, float* __restrict__ t, int n) {
    __shared__ float sW[FIN * FOUT];
    for (int i = threadIdx.x; i < FIN * FOUT; i += blockDim.x) sW[i] = W[i];
    __syncthreads();
    int nd = blockIdx.x * blockDim.x + threadIdx.x;
    if (nd >= n) return;
    float xi[FIN];
#pragma unroll
    for (int k = 0; k < FIN; ++k) xi[k] = x[(size_t)nd * FIN + k];
    float d = dinv[nd];
#pragma unroll
    for (int j = 0; j < FOUT; ++j) {
        float acc = 0.f;
#pragma unroll
        for (int k = 0; k < FIN; ++k) acc = fmaf(xi[k], sW[k * FOUT + j], acc);
        t[(size_t)nd * FOUT + j] = acc * d;
    }
}

// ---------------- gather-aggregate + epilogue ----------------

template<int F, int VEC, bool RELU>
__global__ void k_gather(const int* __restrict__ rowptr, const int* __restrict__ ssrc,
                         const float* __restrict__ t, const float* __restrict__ dinv,
                         const float* __restrict__ b, float* __restrict__ out, int n) {
    constexpr int TPN = F / VEC;
    int i = blockIdx.x * blockDim.x + threadIdx.x;
    int node = i / TPN;
    int fv = i % TPN;
    if (node >= n) return;
    int f0 = fv * VEC;

    float acc[VEC];
    {
        const float* trow = t + (size_t)node * F + f0;
        if constexpr (VEC == 4) {
            float4 v = *reinterpret_cast<const float4*>(trow);
            acc[0] = v.x; acc[1] = v.y; acc[2] = v.z; acc[3] = v.w;
        } else {
            float2 v = *reinterpret_cast<const float2*>(trow);
            acc[0] = v.x; acc[1] = v.y;
        }
    }
    int beg = rowptr[node], end = rowptr[node + 1];
    for (int j = beg; j < end; ++j) {
        int s = ssrc[j];
        const float* trow = t + (size_t)s * F + f0;
        if constexpr (VEC == 4) {
            float4 v = *reinterpret_cast<const float4*>(trow);
            acc[0] += v.x; acc[1] += v.y; acc[2] += v.z; acc[3] += v.w;
        } else {
            float2 v = *reinterpret_cast<const float2*>(trow);
            acc[0] += v.x; acc[1] += v.y;
        }
    }
    float d = dinv[node];
    float* orow = out + (size_t)node * F + f0;
#pragma unroll
    for (int k = 0; k < VEC; ++k) {
        float vv = fmaf(d, acc[k], b[f0 + k]);
        orow[k] = RELU ? fmaxf(vv, 0.f) : vv;
    }
}

// ---------------- launch ----------------

static inline size_t align256(size_t x) { return (x + 255) & ~(size_t)255; }

extern "C" void kernel_launch(void* const* d_in, const int* in_sizes, int n_in,
                              void* d_out, int out_size, void* d_ws, size_t ws_size,
                              hipStream_t stream) {
    const float* x  = (const float*)d_in[0];
    const int*   ei = (const int*)d_in[1];
    const float* W1 = (const float*)d_in[2];
    const float* b1 = (const float*)d_in[3];
    const float* W2 = (const float*)d_in[4];
    const float* b2 = (const float*)d_in[5];
    const float* W3 = (const float*)d_in[6];
    const float* b3 = (const float*)d_in[7];
    float* out = (float*)d_out;

    const int* src = ei;
    const int* dst = ei + NED;

    char* p = (char*)d_ws;
    float* dinv   = (float*)p; p += align256(sizeof(float) * (size_t)NND);
    int*   rowptr = (int*)p;   p += align256(sizeof(int) * (size_t)(NND + 1));
    int*   excl   = (int*)p;   p += align256(sizeof(int) * (size_t)(SCAN_N + 1));
    int*   bsums  = (int*)p;   p += align256(sizeof(int) * 128);
    int*   ssrc   = (int*)p;   p += align256(sizeof(int) * (size_t)NED);
    float* buf0   = (float*)p; p += align256(sizeof(float) * (size_t)NND * 32);
    float* buf1   = (float*)p; p += align256(sizeof(float) * (size_t)NND * 32);
    int*   tmp    = (int*)buf0;  // alias: tmp dead before buf0's first use

    const int B = 256;
    const int gridN = (NND + B - 1) / B;
    const int nScanBlocks = (SCAN_N + 1023) / 1024;  // 98

    // ---- CSR build: histogram -> scan -> partition -> per-bucket fill ----
    k_hist<<<NCHUNK, B, 0, stream>>>(dst, excl);
    k_scan1<<<nScanBlocks, 256, 0, stream>>>(excl, excl, bsums, SCAN_N);  // in-place
    k_scan2<<<1, 128, 0, stream>>>(bsums, nScanBlocks);
    k_scan3<<<(SCAN_N + 1 + B - 1) / B, B, 0, stream>>>(excl, bsums, SCAN_N, NED);
    k_part<<<NCHUNK, B, 0, stream>>>(src, dst, excl, tmp);
    k_bucket<<<NB, B, 0, stream>>>(excl, tmp, ssrc, rowptr, dinv);

    // ---- layer 1: 3 -> 16, relu ----
    k_xw<3, 16><<<gridN, B, 0, stream>>>(x, W1, dinv, buf0, NND);
    k_gather<16, 4, true><<<(NND * 4 + B - 1) / B, B, 0, stream>>>(rowptr, ssrc, buf0, dinv, b1, buf1, NND);

    // ---- layer 2: 16 -> 32, relu ----
    k_xw<16, 32><<<gridN, B, 0, stream>>>(buf1, W2, dinv, buf0, NND);
    k_gather<32, 4, true><<<(NND * 8 + B - 1) / B, B, 0, stream>>>(rowptr, ssrc, buf0, dinv, b2, buf1, NND);

    // ---- layer 3: 32 -> 2, no relu ----
    k_xw<32, 2><<<gridN, B, 0, stream>>>(buf1, W3, dinv, buf0, NND);
    k_gather<2, 2, false><<<(NND + B - 1) / B, B, 0, stream>>>(rowptr, ssrc, buf0, dinv, b3, out, NND);
}

// Round 4
// 212.629 us; speedup vs baseline: 3.9002x; 1.1723x over previous
//
#include <hip/hip_runtime.h>
#include <type_traits>

static constexpr int NND = 100000;        // nodes
static constexpr int NED = 3200000;       // edges (before self-loops)
static constexpr int NB  = (NND + 255) / 256;   // 391 buckets of 256 nodes
static constexpr int NCHUNK = 256;              // edge chunks
static constexpr int EPC = NED / NCHUNK;        // 12500 edges per chunk
static constexpr int SCAN_N = NB * NCHUNK;      // 100096

// ---------------- partition pass 1: per-(chunk,bucket) histogram ----------------

__global__ void k_hist(const int* __restrict__ dst, int* __restrict__ counts) {
    __shared__ int h[NB];
    for (int i = threadIdx.x; i < NB; i += 256) h[i] = 0;
    __syncthreads();
    int c = blockIdx.x;
    int base = c * EPC;
    for (int i = threadIdx.x; i < EPC; i += 256)
        atomicAdd(&h[dst[base + i] >> 8], 1);
    __syncthreads();
    for (int b = threadIdx.x; b < NB; b += 256)
        counts[b * NCHUNK + c] = h[b];   // bucket-major for the scan
}

// ---------------- scan (exclusive), 1024 elems/block ----------------

__global__ void k_scan1(const int* __restrict__ in, int* __restrict__ excl,
                        int* __restrict__ blockSums, int n) {
    __shared__ int lds[256];
    int tid = threadIdx.x;
    int base = blockIdx.x * 1024 + tid * 4;
    int v[4]; int sum = 0;
#pragma unroll
    for (int k = 0; k < 4; ++k) { int idx = base + k; v[k] = (idx < n) ? in[idx] : 0; sum += v[k]; }
    lds[tid] = sum; __syncthreads();
    for (int off = 1; off < 256; off <<= 1) {
        int x = lds[tid];
        int y = (tid >= off) ? lds[tid - off] : 0;
        __syncthreads();
        lds[tid] = x + y;
        __syncthreads();
    }
    int run = lds[tid] - sum;
#pragma unroll
    for (int k = 0; k < 4; ++k) { int idx = base + k; if (idx < n) excl[idx] = run; run += v[k]; }
    if (tid == 0) blockSums[blockIdx.x] = lds[255];
}

__global__ void k_scan2(int* __restrict__ blockSums, int nb) {  // single block, 128 thr
    __shared__ int lds[128];
    int tid = threadIdx.x;
    int v = (tid < nb) ? blockSums[tid] : 0;
    lds[tid] = v; __syncthreads();
    for (int off = 1; off < 128; off <<= 1) {
        int x = lds[tid];
        int y = (tid >= off) ? lds[tid - off] : 0;
        __syncthreads();
        lds[tid] = x + y;
        __syncthreads();
    }
    if (tid < nb) blockSums[tid] = lds[tid] - v;
}

__global__ void k_scan3(int* __restrict__ excl, const int* __restrict__ blockSums,
                        int n, int e) {
    int i = blockIdx.x * blockDim.x + threadIdx.x;
    if (i < n) excl[i] += blockSums[i >> 10];
    if (i == n) excl[n] = e;
}

// ---------------- partition pass 2: scatter into bucket runs ----------------
// pack = src | (dst&255)<<20   (src < 2^20)

__global__ void k_part(const int* __restrict__ src, const int* __restrict__ dst,
                       const int* __restrict__ excl, int* __restrict__ tmp) {
    __shared__ int cur[NB];
    int c = blockIdx.x;
    for (int b = threadIdx.x; b < NB; b += 256) cur[b] = excl[b * NCHUNK + c];
    __syncthreads();
    int base = c * EPC;
    for (int i = threadIdx.x; i < EPC; i += 256) {
        int d = dst[base + i];
        int s = src[base + i];
        int b = d >> 8;
        int pos = atomicAdd(&cur[b], 1);
        tmp[pos] = s | ((d & 255) << 20);
    }
}

// ---------------- per-bucket: deg/dinv/rowptr + final CSR fill ----------------

__global__ void k_bucket(const int* __restrict__ excl, const int* __restrict__ tmp,
                         int* __restrict__ ssrc, int* __restrict__ rowptr,
                         float* __restrict__ dinv) {
    __shared__ int cnt[256];
    __shared__ int lds[256];
    int b = blockIdx.x, t = threadIdx.x;
    int start = excl[b * NCHUNK];
    int end   = excl[(b + 1) * NCHUNK];   // excl[SCAN_N] == NED for last bucket
    cnt[t] = 0;
    __syncthreads();
    for (int i = start + t; i < end; i += 256)
        atomicAdd(&cnt[tmp[i] >> 20], 1);
    __syncthreads();
    int v = cnt[t];
    lds[t] = v; __syncthreads();
    for (int off = 1; off < 256; off <<= 1) {
        int x = lds[t];
        int y = (t >= off) ? lds[t - off] : 0;
        __syncthreads();
        lds[t] = x + y;
        __syncthreads();
    }
    int node = b * 256 + t;
    int rp = start + lds[t] - v;          // global CSR row start
    if (node < NND) {
        rowptr[node] = rp;
        dinv[node] = rsqrtf((float)(v + 1));  // +1 self-loop
    }
    if (b == 0 && t == 0) rowptr[NND] = NED;
    cnt[t] = rp;                          // reuse as running cursor
    __syncthreads();
    for (int i = start + t; i < end; i += 256) {
        int p = tmp[i];
        int pos = atomicAdd(&cnt[p >> 20], 1);
        ssrc[pos] = p & 0xFFFFF;
    }
}

// ---------------- dense t = (x @ W) * dinv ----------------

template<int FIN, int FOUT>
__global__ void k_xw(const float* __restrict__ x, const float* __restrict__ W,
                     const float* __restrict__ dinv, float* __restrict__ t, int n) {
    __shared__ float sW[FIN * FOUT];
    for (int i = threadIdx.x; i < FIN * FOUT; i += blockDim.x) sW[i] = W[i];
    __syncthreads();
    int nd = blockIdx.x * blockDim.x + threadIdx.x;
    if (nd >= n) return;
    float xi[FIN];
#pragma unroll
    for (int k = 0; k < FIN; ++k) xi[k] = x[(size_t)nd * FIN + k];
    float d = dinv[nd];
#pragma unroll
    for (int j = 0; j < FOUT; ++j) {
        float acc = 0.f;
#pragma unroll
        for (int k = 0; k < FIN; ++k) acc = fmaf(xi[k], sW[k * FOUT + j], acc);
        t[(size_t)nd * FOUT + j] = acc * d;
    }
}

// ---------------- gather-aggregate + epilogue (8-deep MLP unroll) ----------------

template<int F, int VEC, bool RELU>
__global__ void k_gather(const int* __restrict__ rowptr, const int* __restrict__ ssrc,
                         const float* __restrict__ t, const float* __restrict__ dinv,
                         const float* __restrict__ b, float* __restrict__ out, int n) {
    constexpr int TPN = F / VEC;
    constexpr int U = 8;                  // unroll depth = outstanding row loads
    using VT = std::conditional_t<VEC == 4, float4, float2>;
    int i = blockIdx.x * blockDim.x + threadIdx.x;
    int node = i / TPN;
    int fv = i % TPN;
    if (node >= n) return;
    int f0 = fv * VEC;

    float acc[VEC];
    {
        VT v = *reinterpret_cast<const VT*>(t + (size_t)node * F + f0);
        const float* vp = reinterpret_cast<const float*>(&v);
#pragma unroll
        for (int c = 0; c < VEC; ++c) acc[c] = vp[c];
    }

    int beg = rowptr[node], end = rowptr[node + 1];
    int j = beg;
    for (; j + U <= end; j += U) {
        int s[U];
#pragma unroll
        for (int k = 0; k < U; ++k) s[k] = ssrc[j + k];
        VT v[U];
#pragma unroll
        for (int k = 0; k < U; ++k)
            v[k] = *reinterpret_cast<const VT*>(t + (size_t)s[k] * F + f0);
#pragma unroll
        for (int k = 0; k < U; ++k) {
            const float* vp = reinterpret_cast<const float*>(&v[k]);
#pragma unroll
            for (int c = 0; c < VEC; ++c) acc[c] += vp[c];
        }
    }
    for (; j < end; ++j) {
        int s = ssrc[j];
        VT v = *reinterpret_cast<const VT*>(t + (size_t)s * F + f0);
        const float* vp = reinterpret_cast<const float*>(&v);
#pragma unroll
        for (int c = 0; c < VEC; ++c) acc[c] += vp[c];
    }

    float d = dinv[node];
    float* orow = out + (size_t)node * F + f0;
#pragma unroll
    for (int c = 0; c < VEC; ++c) {
        float vv = fmaf(d, acc[c], b[f0 + c]);
        orow[c] = RELU ? fmaxf(vv, 0.f) : vv;
    }
}

// ---------------- launch ----------------

static inline size_t align256(size_t x) { return (x + 255) & ~(size_t)255; }

extern "C" void kernel_launch(void* const* d_in, const int* in_sizes, int n_in,
                              void* d_out, int out_size, void* d_ws, size_t ws_size,
                              hipStream_t stream) {
    const float* x  = (const float*)d_in[0];
    const int*   ei = (const int*)d_in[1];
    const float* W1 = (const float*)d_in[2];
    const float* b1 = (const float*)d_in[3];
    const float* W2 = (const float*)d_in[4];
    const float* b2 = (const float*)d_in[5];
    const float* W3 = (const float*)d_in[6];
    const float* b3 = (const float*)d_in[7];
    float* out = (float*)d_out;

    const int* src = ei;
    const int* dst = ei + NED;

    char* p = (char*)d_ws;
    float* dinv   = (float*)p; p += align256(sizeof(float) * (size_t)NND);
    int*   rowptr = (int*)p;   p += align256(sizeof(int) * (size_t)(NND + 1));
    int*   excl   = (int*)p;   p += align256(sizeof(int) * (size_t)(SCAN_N + 1));
    int*   bsums  = (int*)p;   p += align256(sizeof(int) * 128);
    int*   ssrc   = (int*)p;   p += align256(sizeof(int) * (size_t)NED);
    float* buf0   = (float*)p; p += align256(sizeof(float) * (size_t)NND * 32);
    float* buf1   = (float*)p; p += align256(sizeof(float) * (size_t)NND * 32);
    int*   tmp    = (int*)buf0;  // alias: tmp dead before buf0's first use

    const int B = 256;
    const int gridN = (NND + B - 1) / B;
    const int nScanBlocks = (SCAN_N + 1023) / 1024;  // 98

    // ---- CSR build: histogram -> scan -> partition -> per-bucket fill ----
    k_hist<<<NCHUNK, B, 0, stream>>>(dst, excl);
    k_scan1<<<nScanBlocks, 256, 0, stream>>>(excl, excl, bsums, SCAN_N);  // in-place
    k_scan2<<<1, 128, 0, stream>>>(bsums, nScanBlocks);
    k_scan3<<<(SCAN_N + 1 + B - 1) / B, B, 0, stream>>>(excl, bsums, SCAN_N, NED);
    k_part<<<NCHUNK, B, 0, stream>>>(src, dst, excl, tmp);
    k_bucket<<<NB, B, 0, stream>>>(excl, tmp, ssrc, rowptr, dinv);

    // ---- layer 1: 3 -> 16, relu ----
    k_xw<3, 16><<<gridN, B, 0, stream>>>(x, W1, dinv, buf0, NND);
    k_gather<16, 4, true><<<(NND * 4 + B - 1) / B, B, 0, stream>>>(rowptr, ssrc, buf0, dinv, b1, buf1, NND);

    // ---- layer 2: 16 -> 32, relu ----
    k_xw<16, 32><<<gridN, B, 0, stream>>>(buf1, W2, dinv, buf0, NND);
    k_gather<32, 4, true><<<(NND * 8 + B - 1) / B, B, 0, stream>>>(rowptr, ssrc, buf0, dinv, b2, buf1, NND);

    // ---- layer 3: 32 -> 2, no relu ----
    k_xw<32, 2><<<gridN, B, 0, stream>>>(buf1, W3, dinv, buf0, NND);
    k_gather<2, 2, false><<<(NND + B - 1) / B, B, 0, stream>>>(rowptr, ssrc, buf0, dinv, b3, out, NND);
}

// Round 5
// 168.151 us; speedup vs baseline: 4.9318x; 1.2645x over previous
//
#include <hip/hip_runtime.h>

static constexpr int NND = 100000;        // nodes
static constexpr int NED = 3200000;       // edges (before self-loops)
static constexpr int NB  = (NND + 255) / 256;   // 391 buckets of 256 nodes
static constexpr int NCHUNK = 256;              // edge chunks
static constexpr int EPC = NED / NCHUNK;        // 12500 edges per chunk
static constexpr int SCAN_N = NB * NCHUNK;      // 100096

// ---------------- partition pass 1: per-(chunk,bucket) histogram ----------------

__global__ void k_hist(const int* __restrict__ dst, int* __restrict__ counts) {
    __shared__ int h[NB];
    for (int i = threadIdx.x; i < NB; i += 256) h[i] = 0;
    __syncthreads();
    int c = blockIdx.x;
    int base = c * EPC;
    for (int i = threadIdx.x; i < EPC; i += 256)
        atomicAdd(&h[dst[base + i] >> 8], 1);
    __syncthreads();
    for (int b = threadIdx.x; b < NB; b += 256)
        counts[b * NCHUNK + c] = h[b];   // bucket-major for the scan
}

// ---------------- scan (exclusive), 1024 elems/block ----------------

__global__ void k_scan1(const int* __restrict__ in, int* __restrict__ excl,
                        int* __restrict__ blockSums, int n) {
    __shared__ int lds[256];
    int tid = threadIdx.x;
    int base = blockIdx.x * 1024 + tid * 4;
    int v[4]; int sum = 0;
#pragma unroll
    for (int k = 0; k < 4; ++k) { int idx = base + k; v[k] = (idx < n) ? in[idx] : 0; sum += v[k]; }
    lds[tid] = sum; __syncthreads();
    for (int off = 1; off < 256; off <<= 1) {
        int x = lds[tid];
        int y = (tid >= off) ? lds[tid - off] : 0;
        __syncthreads();
        lds[tid] = x + y;
        __syncthreads();
    }
    int run = lds[tid] - sum;
#pragma unroll
    for (int k = 0; k < 4; ++k) { int idx = base + k; if (idx < n) excl[idx] = run; run += v[k]; }
    if (tid == 0) blockSums[blockIdx.x] = lds[255];
}

__global__ void k_scan2(int* __restrict__ blockSums, int nb) {  // single block, 128 thr
    __shared__ int lds[128];
    int tid = threadIdx.x;
    int v = (tid < nb) ? blockSums[tid] : 0;
    lds[tid] = v; __syncthreads();
    for (int off = 1; off < 128; off <<= 1) {
        int x = lds[tid];
        int y = (tid >= off) ? lds[tid - off] : 0;
        __syncthreads();
        lds[tid] = x + y;
        __syncthreads();
    }
    if (tid < nb) blockSums[tid] = lds[tid] - v;
}

__global__ void k_scan3(int* __restrict__ excl, const int* __restrict__ blockSums,
                        int n, int e) {
    int i = blockIdx.x * blockDim.x + threadIdx.x;
    if (i < n) excl[i] += blockSums[i >> 10];
    if (i == n) excl[n] = e;
}

// ---------------- partition pass 2: scatter into bucket runs ----------------
// pack = src | (dst&255)<<20   (src < 2^20)

__global__ void k_part(const int* __restrict__ src, const int* __restrict__ dst,
                       const int* __restrict__ excl, int* __restrict__ tmp) {
    __shared__ int cur[NB];
    int c = blockIdx.x;
    for (int b = threadIdx.x; b < NB; b += 256) cur[b] = excl[b * NCHUNK + c];
    __syncthreads();
    int base = c * EPC;
    for (int i = threadIdx.x; i < EPC; i += 256) {
        int d = dst[base + i];
        int s = src[base + i];
        int b = d >> 8;
        int pos = atomicAdd(&cur[b], 1);
        tmp[pos] = s | ((d & 255) << 20);
    }
}

// ---------------- per-bucket: deg/dinv/rowptr + final CSR fill ----------------

__global__ void k_bucket(const int* __restrict__ excl, const int* __restrict__ tmp,
                         int* __restrict__ ssrc, int* __restrict__ rowptr,
                         float* __restrict__ dinv) {
    __shared__ int cnt[256];
    __shared__ int lds[256];
    int b = blockIdx.x, t = threadIdx.x;
    int start = excl[b * NCHUNK];
    int end   = excl[(b + 1) * NCHUNK];
    cnt[t] = 0;
    __syncthreads();
    for (int i = start + t; i < end; i += 256)
        atomicAdd(&cnt[tmp[i] >> 20], 1);
    __syncthreads();
    int v = cnt[t];
    lds[t] = v; __syncthreads();
    for (int off = 1; off < 256; off <<= 1) {
        int x = lds[t];
        int y = (t >= off) ? lds[t - off] : 0;
        __syncthreads();
        lds[t] = x + y;
        __syncthreads();
    }
    int node = b * 256 + t;
    int rp = start + lds[t] - v;
    if (node < NND) {
        rowptr[node] = rp;
        dinv[node] = rsqrtf((float)(v + 1));  // +1 self-loop
    }
    if (b == 0 && t == 0) rowptr[NND] = NED;
    cnt[t] = rp;
    __syncthreads();
    for (int i = start + t; i < end; i += 256) {
        int p = tmp[i];
        int pos = atomicAdd(&cnt[p >> 20], 1);
        ssrc[pos] = p & 0xFFFFF;
    }
}

// ---------------- t4[n] = {x[n]*dinv[n], pad0} ----------------

__global__ void k_prep1(const float* __restrict__ x, const float* __restrict__ dinv,
                        float4* __restrict__ t4, int n) {
    int i = blockIdx.x * blockDim.x + threadIdx.x;
    if (i >= n) return;
    float d = dinv[i];
    const float* xr = x + (size_t)i * 3;
    t4[i] = make_float4(xr[0] * d, xr[1] * d, xr[2] * d, 0.f);
}

// ---------------- layer1: gather 4-wide + fused 3->16 matmul ----------------
// t16[n,:] = relu( (dinv[n]*agg) @ W1 + b1 ) * dinv[n],  agg = t4[n] + sum t4[src]

__global__ void k_g4mm1(const int* __restrict__ rowptr, const int* __restrict__ ssrc,
                        const float4* __restrict__ t4, const float* __restrict__ dinv,
                        const float* __restrict__ W1, const float* __restrict__ b1,
                        float* __restrict__ t16, int n) {
    __shared__ float sW[48];
    __shared__ float sb[16];
    if (threadIdx.x < 48) sW[threadIdx.x] = W1[threadIdx.x];
    if (threadIdx.x < 16) sb[threadIdx.x] = b1[threadIdx.x];
    __syncthreads();
    int node = blockIdx.x * blockDim.x + threadIdx.x;
    if (node >= n) return;

    float4 a = t4[node];
    float a0 = a.x, a1 = a.y, a2 = a.z;
    int beg = rowptr[node], end = rowptr[node + 1];
    constexpr int U = 8;
    int j = beg;
    for (; j + U <= end; j += U) {
        int s[U];
#pragma unroll
        for (int k = 0; k < U; ++k) s[k] = ssrc[j + k];
        float4 v[U];
#pragma unroll
        for (int k = 0; k < U; ++k) v[k] = t4[s[k]];
#pragma unroll
        for (int k = 0; k < U; ++k) { a0 += v[k].x; a1 += v[k].y; a2 += v[k].z; }
    }
    for (; j < end; ++j) {
        float4 v = t4[ssrc[j]];
        a0 += v.x; a1 += v.y; a2 += v.z;
    }
    float d = dinv[node];
    float p0 = a0 * d, p1 = a1 * d, p2 = a2 * d;
    float* orow = t16 + (size_t)node * 16;
#pragma unroll
    for (int q = 0; q < 4; ++q) {
        float4 o;
        float* op = reinterpret_cast<float*>(&o);
#pragma unroll
        for (int r = 0; r < 4; ++r) {
            int jj = q * 4 + r;
            float h = fmaf(p0, sW[jj], fmaf(p1, sW[16 + jj], fmaf(p2, sW[32 + jj], sb[jj])));
            op[r] = fmaxf(h, 0.f) * d;
        }
        *reinterpret_cast<float4*>(orow + q * 4) = o;
    }
}

// ---------------- layer2: gather 16-wide -> u16 = dinv*(t16[n] + sum t16[src]) ----------------

__global__ void k_g16u(const int* __restrict__ rowptr, const int* __restrict__ ssrc,
                       const float* __restrict__ t16, const float* __restrict__ dinv,
                       float* __restrict__ u16, int n) {
    constexpr int TPN = 4, U = 8;
    int i = blockIdx.x * blockDim.x + threadIdx.x;
    int node = i / TPN;
    int fv = i % TPN;
    if (node >= n) return;
    int f0 = fv * 4;

    float4 acc = *reinterpret_cast<const float4*>(t16 + (size_t)node * 16 + f0);
    int beg = rowptr[node], end = rowptr[node + 1];
    int j = beg;
    for (; j + U <= end; j += U) {
        int s[U];
#pragma unroll
        for (int k = 0; k < U; ++k) s[k] = ssrc[j + k];
        float4 v[U];
#pragma unroll
        for (int k = 0; k < U; ++k)
            v[k] = *reinterpret_cast<const float4*>(t16 + (size_t)s[k] * 16 + f0);
#pragma unroll
        for (int k = 0; k < U; ++k) {
            acc.x += v[k].x; acc.y += v[k].y; acc.z += v[k].z; acc.w += v[k].w;
        }
    }
    for (; j < end; ++j) {
        float4 v = *reinterpret_cast<const float4*>(t16 + (size_t)ssrc[j] * 16 + f0);
        acc.x += v.x; acc.y += v.y; acc.z += v.z; acc.w += v.w;
    }
    float d = dinv[node];
    acc.x *= d; acc.y *= d; acc.z *= d; acc.w *= d;
    *reinterpret_cast<float4*>(u16 + (size_t)node * 16 + f0) = acc;
}

// ---------------- per-node fused: h2 = relu(u16@W2+b2); t3 = (h2@W3)*dinv ----------------

__global__ void k_mm23(const float* __restrict__ u16, const float* __restrict__ W2,
                       const float* __restrict__ b2, const float* __restrict__ W3,
                       const float* __restrict__ dinv, float2* __restrict__ t3, int n) {
    __shared__ float sW2[512];
    __shared__ float sb2[32];
    __shared__ float sW3[64];
    for (int i = threadIdx.x; i < 512; i += 256) sW2[i] = W2[i];
    if (threadIdx.x < 32) sb2[threadIdx.x] = b2[threadIdx.x];
    if (threadIdx.x < 64) sW3[threadIdx.x] = W3[threadIdx.x];
    __syncthreads();
    int node = blockIdx.x * blockDim.x + threadIdx.x;
    if (node >= n) return;
    float u[16];
#pragma unroll
    for (int q = 0; q < 4; ++q) {
        float4 v = *reinterpret_cast<const float4*>(u16 + (size_t)node * 16 + q * 4);
        u[q * 4 + 0] = v.x; u[q * 4 + 1] = v.y; u[q * 4 + 2] = v.z; u[q * 4 + 3] = v.w;
    }
    float t30 = 0.f, t31 = 0.f;
#pragma unroll
    for (int jj = 0; jj < 32; ++jj) {
        float h = sb2[jj];
#pragma unroll
        for (int k = 0; k < 16; ++k) h = fmaf(u[k], sW2[k * 32 + jj], h);
        h = fmaxf(h, 0.f);
        t30 = fmaf(h, sW3[jj * 2 + 0], t30);
        t31 = fmaf(h, sW3[jj * 2 + 1], t31);
    }
    float d = dinv[node];
    t3[node] = make_float2(t30 * d, t31 * d);
}

// ---------------- layer3: gather 2-wide + bias ----------------

__global__ void k_g2(const int* __restrict__ rowptr, const int* __restrict__ ssrc,
                     const float2* __restrict__ t3, const float* __restrict__ dinv,
                     const float* __restrict__ b3, float2* __restrict__ out, int n) {
    constexpr int U = 8;
    int node = blockIdx.x * blockDim.x + threadIdx.x;
    if (node >= n) return;
    float2 t = t3[node];
    float a0 = t.x, a1 = t.y;
    int beg = rowptr[node], end = rowptr[node + 1];
    int j = beg;
    for (; j + U <= end; j += U) {
        int s[U];
#pragma unroll
        for (int k = 0; k < U; ++k) s[k] = ssrc[j + k];
        float2 v[U];
#pragma unroll
        for (int k = 0; k < U; ++k) v[k] = t3[s[k]];
#pragma unroll
        for (int k = 0; k < U; ++k) { a0 += v[k].x; a1 += v[k].y; }
    }
    for (; j < end; ++j) {
        float2 v = t3[ssrc[j]];
        a0 += v.x; a1 += v.y;
    }
    float d = dinv[node];
    out[node] = make_float2(fmaf(d, a0, b3[0]), fmaf(d, a1, b3[1]));
}

// ---------------- launch ----------------

static inline size_t align256(size_t x) { return (x + 255) & ~(size_t)255; }

extern "C" void kernel_launch(void* const* d_in, const int* in_sizes, int n_in,
                              void* d_out, int out_size, void* d_ws, size_t ws_size,
                              hipStream_t stream) {
    const float* x  = (const float*)d_in[0];
    const int*   ei = (const int*)d_in[1];
    const float* W1 = (const float*)d_in[2];
    const float* b1 = (const float*)d_in[3];
    const float* W2 = (const float*)d_in[4];
    const float* b2 = (const float*)d_in[5];
    const float* W3 = (const float*)d_in[6];
    const float* b3 = (const float*)d_in[7];
    float2* out = (float2*)d_out;

    const int* src = ei;
    const int* dst = ei + NED;

    char* p = (char*)d_ws;
    float* dinv   = (float*)p; p += align256(sizeof(float) * (size_t)NND);
    int*   rowptr = (int*)p;   p += align256(sizeof(int) * (size_t)(NND + 1));
    int*   excl   = (int*)p;   p += align256(sizeof(int) * (size_t)(SCAN_N + 1));
    int*   bsums  = (int*)p;   p += align256(sizeof(int) * 128);
    int*   ssrc   = (int*)p;   p += align256(sizeof(int) * (size_t)NED);
    float4* t4    = (float4*)p; p += align256(sizeof(float4) * (size_t)NND);
    float2* t3    = (float2*)p; p += align256(sizeof(float2) * (size_t)NND);
    float* regA   = (float*)p; p += align256(sizeof(float) * (size_t)NND * 32);  // tmp | t16+u16
    int*   tmp    = (int*)regA;                 // dead after k_bucket
    float* t16    = regA;                       // [NND][16]
    float* u16    = regA + (size_t)NND * 16;    // [NND][16]

    const int B = 256;
    const int gridN = (NND + B - 1) / B;
    const int nScanBlocks = (SCAN_N + 1023) / 1024;  // 98

    // ---- CSR build ----
    k_hist<<<NCHUNK, B, 0, stream>>>(dst, excl);
    k_scan1<<<nScanBlocks, 256, 0, stream>>>(excl, excl, bsums, SCAN_N);
    k_scan2<<<1, 128, 0, stream>>>(bsums, nScanBlocks);
    k_scan3<<<(SCAN_N + 1 + B - 1) / B, B, 0, stream>>>(excl, bsums, SCAN_N, NED);
    k_part<<<NCHUNK, B, 0, stream>>>(src, dst, excl, tmp);
    k_bucket<<<NB, B, 0, stream>>>(excl, tmp, ssrc, rowptr, dinv);

    // ---- layer 1: aggregate 4-wide, fused 3->16 ----
    k_prep1<<<gridN, B, 0, stream>>>(x, dinv, t4, NND);
    k_g4mm1<<<gridN, B, 0, stream>>>(rowptr, ssrc, t4, dinv, W1, b1, t16, NND);

    // ---- layer 2: aggregate 16-wide, then fused W2+relu+W3 ----
    k_g16u<<<(NND * 4 + B - 1) / B, B, 0, stream>>>(rowptr, ssrc, t16, dinv, u16, NND);
    k_mm23<<<gridN, B, 0, stream>>>(u16, W2, b2, W3, dinv, t3, NND);

    // ---- layer 3: gather 2-wide ----
    k_g2<<<gridN, B, 0, stream>>>(rowptr, ssrc, t3, dinv, b3, out, NND);
}